// Round 2
// baseline (183.230 us; speedup 1.0000x reference)
//
#include <hip/hip_runtime.h>
#include <hip/hip_bf16.h>

#define NE 32
#define MM 1024
#define KK 512
#define NN 512
#define BM 128
#define BN 128
#define BK 32
#define LDST (BK + 8)   // bf16 elems per LDS row (+8 pad -> 80B stride, 16B-aligned)
#define NMT (MM / BM)   // 8 m-tiles per expert
#define NNT (NN / BN)   // 4 n-tiles per expert

typedef __attribute__((ext_vector_type(8))) short bf16x8;
typedef __attribute__((ext_vector_type(4))) short shortx4;
typedef __attribute__((ext_vector_type(4))) float floatx4;

__device__ __forceinline__ short f2bf(float f) {
  union { __hip_bfloat16 b; short s; } u;
  u.b = __float2bfloat16(f);   // RNE
  return u.s;
}

// Queue layout in d_ws (uint32):
//   q[0] = atomic work counter (init 0 here; ws is 0xAA-poisoned each launch)
//   q[1] = total item count
//   q[2..] = items: bit31 = zero-fill flag; [23:16]=e, [15:8]=mt, [7:0]=nt
// GEMM items first (grouped by expert -> L2/L3 locality), zero stripes last.
extern "C" __global__ void prepass(const int* __restrict__ cnts,
                                   unsigned int* __restrict__ q) {
  if (threadIdx.x == 0 && blockIdx.x == 0) {
    int w = 2;
    for (int e = 0; e < NE; ++e) {
      int vt = (cnts[e] + BM - 1) / BM;
      for (int mt = 0; mt < vt; ++mt)
        for (int nt = 0; nt < NNT; ++nt)
          q[w++] = ((unsigned)e << 16) | ((unsigned)mt << 8) | (unsigned)nt;
    }
    for (int e = 0; e < NE; ++e) {
      int vt = (cnts[e] + BM - 1) / BM;
      for (int mt = vt; mt < NMT; ++mt)
        q[w++] = 0x80000000u | ((unsigned)e << 16) | ((unsigned)mt << 8);
    }
    q[1] = (unsigned)(w - 2);
    q[0] = 0u;
  }
}

extern "C" __global__ __launch_bounds__(256, 2)
void expert_gemm(const float* __restrict__ A, const float* __restrict__ B,
                 const int* __restrict__ cnts, float* __restrict__ C,
                 unsigned int* __restrict__ q)
{
  __shared__ __align__(16) short lA[BM * LDST];
  __shared__ __align__(16) short lB[BN * LDST];
  __shared__ unsigned int item_s;

  const int tid  = threadIdx.x;
  const int wave = tid >> 6;
  const int lane = tid & 63;
  const int wm = (wave >> 1) * 64;
  const int wn = (wave & 1) * 64;
  const int fr = lane & 15;
  const int kh = lane >> 4;
  const int srow = tid >> 3;
  const int scol = (tid & 7) << 2;
  const unsigned total = q[1];

  for (;;) {
    __syncthreads();                       // protect item_s + LDS reuse across items
    if (tid == 0) item_s = atomicAdd(&q[0], 1u);
    __syncthreads();
    unsigned idx = item_s;
    if (idx >= total) break;
    unsigned it = q[2 + idx];
    int e  = (it >> 16) & 0xFF;
    int mt = (it >> 8) & 0xFF;

    if (it & 0x80000000u) {
      // zero-fill a full 128x512 stripe (harness poisons d_out to 0xAA)
      float* Ce = C + ((size_t)e * MM + mt * BM) * NN;
      float4 z = make_float4(0.f, 0.f, 0.f, 0.f);
#pragma unroll
      for (int i = 0; i < 64; ++i) {
        int fidx = i * 256 + tid;          // float4 index within stripe (128*128)
        int r = fidx >> 7;                 // 128 float4 per row
        int c = (fidx & 127) << 2;
        *(float4*)(Ce + (size_t)r * NN + c) = z;
      }
      continue;
    }

    int nt = it & 0xFF;
    int m0 = mt * BM, n0 = nt * BN;
    int cnt = cnts[e];
    const float* Ae = A + ((size_t)e * MM + m0) * KK;
    const float* Be = B + ((size_t)e * NN + n0) * KK;
    float* Ce = C + ((size_t)e * MM + m0) * NN + n0;

    floatx4 acc[4][4] = {};
    float4 ra[4], rbv[4];
#pragma unroll
    for (int p = 0; p < 4; ++p) {
      ra[p]  = *(const float4*)(Ae + (size_t)(srow + p * 32) * KK + scol);
      rbv[p] = *(const float4*)(Be + (size_t)(srow + p * 32) * KK + scol);
    }

    for (int kt = 0; kt < KK; kt += BK) {
      __syncthreads();
#pragma unroll
      for (int p = 0; p < 4; ++p) {
        shortx4 va = { f2bf(ra[p].x),  f2bf(ra[p].y),  f2bf(ra[p].z),  f2bf(ra[p].w)  };
        shortx4 vb = { f2bf(rbv[p].x), f2bf(rbv[p].y), f2bf(rbv[p].z), f2bf(rbv[p].w) };
        *(shortx4*)(lA + (srow + p * 32) * LDST + scol) = va;
        *(shortx4*)(lB + (srow + p * 32) * LDST + scol) = vb;
      }
      __syncthreads();

      if (kt + BK < KK) {
#pragma unroll
        for (int p = 0; p < 4; ++p) {
          ra[p]  = *(const float4*)(Ae + (size_t)(srow + p * 32) * KK + kt + BK + scol);
          rbv[p] = *(const float4*)(Be + (size_t)(srow + p * 32) * KK + kt + BK + scol);
        }
      }

      bf16x8 af[4], bfv[4];
#pragma unroll
      for (int i = 0; i < 4; ++i) {
        af[i]  = *(bf16x8*)(lA + (wm + i * 16 + fr) * LDST + kh * 8);
        bfv[i] = *(bf16x8*)(lB + (wn + i * 16 + fr) * LDST + kh * 8);
      }
#pragma unroll
      for (int i = 0; i < 4; ++i)
#pragma unroll
        for (int j = 0; j < 4; ++j)
          acc[i][j] = __builtin_amdgcn_mfma_f32_16x16x32_bf16(af[i], bfv[j], acc[i][j], 0, 0, 0);
    }

    // epilogue: C/D layout col=lane&15, row=(lane>>4)*4+reg
    const int rb_ = (lane >> 4) * 4;
#pragma unroll
    for (int i = 0; i < 4; ++i) {
#pragma unroll
      for (int r = 0; r < 4; ++r) {
        int row = wm + i * 16 + rb_ + r;
        bool valid = (m0 + row) < cnt;
#pragma unroll
        for (int j = 0; j < 4; ++j) {
          int col = wn + j * 16 + fr;
          Ce[(size_t)row * NN + col] = valid ? acc[i][j][r] : 0.0f;
        }
      }
    }
  }
}

extern "C" void kernel_launch(void* const* d_in, const int* in_sizes, int n_in,
                              void* d_out, int out_size, void* d_ws, size_t ws_size,
                              hipStream_t stream) {
  const float* A    = (const float*)d_in[0];
  const float* B    = (const float*)d_in[1];
  const int*   cnts = (const int*)d_in[2];
  float*       C    = (float*)d_out;
  unsigned int* q   = (unsigned int*)d_ws;

  hipLaunchKernelGGL(prepass, dim3(1), dim3(64), 0, stream, cnts, q);
  // 512 blocks = 2 blocks/CU resident, 8 waves/CU; ~690 queue items avg
  hipLaunchKernelGGL(expert_gemm, dim3(512), dim3(256), 0, stream, A, B, cnts, C, q);
}

// Round 3
// 159.356 us; speedup vs baseline: 1.1498x; 1.1498x over previous
//
#include <hip/hip_runtime.h>
#include <hip/hip_bf16.h>

#define NE 32
#define MM 1024
#define KK 512
#define NN 512
#define BM 128
#define BN 128
#define BK 32   // bf16 elems per LDS row = 64 B = 4 x 16B units, XOR-swizzled

typedef __attribute__((ext_vector_type(8))) short bf16x8;
typedef __attribute__((ext_vector_type(4))) float floatx4;

__device__ __forceinline__ short f2bf(float f) {
  union { __hip_bfloat16 b; short s; } u;
  u.b = __float2bfloat16(f);   // RNE
  return u.s;
}

// One item per block, decoded from cnts (no queue/atomics/prepass):
//   items [0, 4*sum(vt))            : GEMM tiles, expert-major, mt-major, nt fastest
//   items [4*sum(vt), total)        : zero-fill 128x512 stripes (rows >= cnt)
//   total = 256 + 3*sum(vt) <= 1024 always -> grid 1024 covers everything.
extern "C" __global__ __launch_bounds__(256, 4)
void expert_gemm(const float* __restrict__ A, const float* __restrict__ B,
                 const int* __restrict__ cnts, float* __restrict__ C)
{
  const int b   = blockIdx.x;
  const int tid = threadIdx.x;

  int e = -1, mt = 0, nt = 0;
  int acc = 0;
#pragma unroll 1
  for (int i = 0; i < NE; ++i) {
    int vt = (cnts[i] + BM - 1) >> 7;
    int c4 = vt << 2;
    if (e < 0 && b < acc + c4) { int r = b - acc; e = i; mt = r >> 2; nt = r & 3; }
    acc += c4;
  }
  if (e < 0) {
    int z = b - acc, a2 = 0;
#pragma unroll 1
    for (int i = 0; i < NE; ++i) {
      int vt = (cnts[i] + BM - 1) >> 7;
      int c = 8 - vt;
      if (e < 0 && z < a2 + c) { e = i; mt = vt + (z - a2); }
      a2 += c;
    }
    if (e < 0) return;   // beyond total item count
    // zero-fill a 128x512 stripe (harness poisons d_out to 0xAA each launch)
    float* Ce = C + ((size_t)e * MM + mt * BM) * NN;
    float4 zf = make_float4(0.f, 0.f, 0.f, 0.f);
#pragma unroll
    for (int i = 0; i < 64; ++i) {
      int fidx = i * 256 + tid;
      int r = fidx >> 7, c = (fidx & 127) << 2;
      *(float4*)(Ce + (size_t)r * NN + c) = zf;
    }
    return;
  }

  // ---- GEMM tile: C[e][m0:m0+128][n0:n0+128] = A[e] @ B[e]^T ----
  const int m0 = mt * BM, n0 = nt * BN;
  const int cnt = cnts[e];
  const float* Ae = A + ((size_t)e * MM + m0) * KK;
  const float* Be = B + ((size_t)e * NN + n0) * KK;
  float* Ce = C + ((size_t)e * MM + m0) * NN + n0;

  // Swizzled LDS: row r (64 B = 4 units of 16 B); unit u stored at physical
  // unit (r*4 + (u ^ (r&3))). Both ds_write_b128 and ds_read_b128 then hit
  // the 8-phase LDS BW floor with zero bank conflicts.
  __shared__ __align__(16) short lA[BM * BK];  // 8 KB
  __shared__ __align__(16) short lB[BN * BK];  // 8 KB

  const int wave = tid >> 6, lane = tid & 63;
  const int wm = (wave >> 1) * 64, wn = (wave & 1) * 64;
  const int fr = lane & 15, kh = lane >> 4;

  const int srow = tid >> 2;   // staging row (0..63; +64 on pass 1)
  const int su   = tid & 3;    // 16B unit within row -> floats [su*8, su*8+8)

  floatx4 acc4[4][4] = {};

  for (int kt = 0; kt < KK; kt += BK) {
    // issue all global loads for this K-slab up front (latency overlaps barrier)
    float4 a0[2], a1[2], b0[2], b1[2];
#pragma unroll
    for (int p = 0; p < 2; ++p) {
      int row = srow + (p << 6);
      int col = kt + (su << 3);
      a0[p] = *(const float4*)(Ae + (size_t)row * KK + col);
      a1[p] = *(const float4*)(Ae + (size_t)row * KK + col + 4);
      b0[p] = *(const float4*)(Be + (size_t)row * KK + col);
      b1[p] = *(const float4*)(Be + (size_t)row * KK + col + 4);
    }

    __syncthreads();   // previous iteration's ds_reads complete before overwrite
#pragma unroll
    for (int p = 0; p < 2; ++p) {
      int row = srow + (p << 6);
      int unit = (row << 2) + (su ^ (row & 3));
      bf16x8 va = { f2bf(a0[p].x), f2bf(a0[p].y), f2bf(a0[p].z), f2bf(a0[p].w),
                    f2bf(a1[p].x), f2bf(a1[p].y), f2bf(a1[p].z), f2bf(a1[p].w) };
      bf16x8 vb = { f2bf(b0[p].x), f2bf(b0[p].y), f2bf(b0[p].z), f2bf(b0[p].w),
                    f2bf(b1[p].x), f2bf(b1[p].y), f2bf(b1[p].z), f2bf(b1[p].w) };
      *(bf16x8*)(lA + (unit << 3)) = va;
      *(bf16x8*)(lB + (unit << 3)) = vb;
    }
    __syncthreads();

    bf16x8 af[4], bfv[4];
#pragma unroll
    for (int i = 0; i < 4; ++i) {
      int rA = wm + (i << 4) + fr;
      af[i]  = *(const bf16x8*)(lA + ((((rA << 2) + (kh ^ (rA & 3)))) << 3));
      int rB = wn + (i << 4) + fr;
      bfv[i] = *(const bf16x8*)(lB + ((((rB << 2) + (kh ^ (rB & 3)))) << 3));
    }
#pragma unroll
    for (int i = 0; i < 4; ++i)
#pragma unroll
      for (int j = 0; j < 4; ++j)
        acc4[i][j] = __builtin_amdgcn_mfma_f32_16x16x32_bf16(af[i], bfv[j], acc4[i][j], 0, 0, 0);
  }

  // epilogue: C/D layout col=lane&15, row=(lane>>4)*4+reg (m89/m91-verified)
  const int rb_ = (lane >> 4) * 4;
#pragma unroll
  for (int i = 0; i < 4; ++i) {
#pragma unroll
    for (int r = 0; r < 4; ++r) {
      int row = wm + i * 16 + rb_ + r;
      bool valid = (m0 + row) < cnt;
#pragma unroll
      for (int j = 0; j < 4; ++j) {
        int col = wn + j * 16 + fr;
        Ce[(size_t)row * NN + col] = valid ? acc4[i][j][r] : 0.0f;
      }
    }
  }
}

extern "C" void kernel_launch(void* const* d_in, const int* in_sizes, int n_in,
                              void* d_out, int out_size, void* d_ws, size_t ws_size,
                              hipStream_t stream) {
  const float* A    = (const float*)d_in[0];
  const float* B    = (const float*)d_in[1];
  const int*   cnts = (const int*)d_in[2];
  float*       C    = (float*)d_out;

  // total items <= 1024 structurally; one item per block, decoded on-device
  hipLaunchKernelGGL(expert_gemm, dim3(1024), dim3(256), 0, stream, A, B, cnts, C);
}